// Round 1
// baseline (1013.361 us; speedup 1.0000x reference)
//
#include <hip/hip_runtime.h>
#include <hip/hip_bf16.h>

// Problem constants
#define C_CLASS 64
#define C_GROUPS 8
#define C_GSIZE 32
#define C_D 2048      // IN_CH
#define C_O 256       // OUT_CH
#define C_P 5         // NUM_PROTO
#define C_M (C_CLASS*C_GROUPS*C_GSIZE)   // 16384 rows of feats

typedef __bf16 bf16;
typedef bf16 bf16x8 __attribute__((ext_vector_type(8)));
typedef bf16 bf16x4 __attribute__((ext_vector_type(4)));
typedef float floatx4 __attribute__((ext_vector_type(4)));

// ---------------- fp32 -> bf16 conversion (vectorized) ----------------
__global__ __launch_bounds__(256) void conv_kernel(const float* __restrict__ src,
                                                   bf16* __restrict__ dst, int n4) {
    int i = blockIdx.x * 256 + threadIdx.x;
    if (i < n4) {
        float4 v = ((const float4*)src)[i];
        bf16x4 b;
        b[0] = (bf16)v.x; b[1] = (bf16)v.y; b[2] = (bf16)v.z; b[3] = (bf16)v.w;
        ((bf16x4*)dst)[i] = b;
    }
}

// ---------------- bf16 NT GEMM: C[M,N] = A[M,K] . B[N,K]^T ----------------
// 128x128 tile, BK=32, 4 waves (2x2), each wave 4x4 MFMA 16x16x32 tiles.
// EPI=0: Cf = acc (fp32). EPI=1: Cb = bf16(resid + relu(acc)).
template<int EPI>
__global__ __launch_bounds__(256) void gemm_nt(const bf16* __restrict__ A,
                                               const bf16* __restrict__ B,
                                               int M, int N, int K,
                                               float* __restrict__ Cf,
                                               bf16* __restrict__ Cb,
                                               const float* __restrict__ resid) {
    __shared__ bf16 sA[128 * 32];
    __shared__ bf16 sB[128 * 32];

    const int tid  = threadIdx.x;
    const int m0   = blockIdx.x * 128;
    const int n0   = blockIdx.y * 128;
    const int lane = tid & 63;
    const int wave = tid >> 6;
    const int wm   = (wave >> 1) * 64;
    const int wn   = (wave & 1) * 64;

    // staging map: 256 threads * 16B -> 64 rows x 64B per sweep, 2 sweeps each tile
    const int sr = tid >> 2;          // 0..63
    const int sc = (tid & 3) * 8;     // bf16 col: 0,8,16,24

    const bf16* aPtr = A + (long)(m0 + sr) * K + sc;
    const bf16* bPtr = B + (long)(n0 + sr) * K + sc;

    floatx4 acc[4][4];
#pragma unroll
    for (int i = 0; i < 4; i++)
#pragma unroll
        for (int j = 0; j < 4; j++) acc[i][j] = (floatx4){0.f, 0.f, 0.f, 0.f};

    const int kk = (lane >> 4) * 8;   // k offset within BK=32
    const int rr = lane & 15;         // row within 16x16 tile

    for (int k0 = 0; k0 < K; k0 += 32) {
        int4 a0 = *(const int4*)(aPtr + k0);
        int4 a1 = *(const int4*)(aPtr + (long)64 * K + k0);
        int4 b0 = *(const int4*)(bPtr + k0);
        int4 b1 = *(const int4*)(bPtr + (long)64 * K + k0);
        __syncthreads();
        *(int4*)&sA[sr * 32 + sc]        = a0;
        *(int4*)&sA[(sr + 64) * 32 + sc] = a1;
        *(int4*)&sB[sr * 32 + sc]        = b0;
        *(int4*)&sB[(sr + 64) * 32 + sc] = b1;
        __syncthreads();

        bf16x8 af[4], bff[4];
#pragma unroll
        for (int i = 0; i < 4; i++) {
            af[i]  = *(const bf16x8*)&sA[(wm + i * 16 + rr) * 32 + kk];
            bff[i] = *(const bf16x8*)&sB[(wn + i * 16 + rr) * 32 + kk];
        }
#pragma unroll
        for (int i = 0; i < 4; i++)
#pragma unroll
            for (int j = 0; j < 4; j++)
                acc[i][j] = __builtin_amdgcn_mfma_f32_16x16x32_bf16(af[i], bff[j], acc[i][j], 0, 0, 0);
    }

    // epilogue: C/D layout col=lane&15, row=(lane>>4)*4+reg  [m89/m91 verified]
    const int cn    = lane & 15;
    const int rbase = (lane >> 4) * 4;
#pragma unroll
    for (int i = 0; i < 4; i++) {
#pragma unroll
        for (int j = 0; j < 4; j++) {
            int gn = n0 + wn + j * 16 + cn;
#pragma unroll
            for (int r = 0; r < 4; r++) {
                int gm = m0 + wm + i * 16 + rbase + r;
                long idx = (long)gm * N + gn;
                float v = acc[i][j][r];
                if (EPI == 0) {
                    Cf[idx] = v;
                } else {
                    Cb[idx] = (bf16)(resid[idx] + fmaxf(v, 0.f));
                }
            }
        }
    }
}

// ---------------- per-(c,g) inner attention (fp32), writes ctx as bf16 ----------------
__global__ __launch_bounds__(256) void inner_attn_kernel(const float* __restrict__ X,
                                                         const float* __restrict__ e,
                                                         bf16* __restrict__ ctx) {
    __shared__ float se[32][257];
    __shared__ float satt[32][33];
    const int bid = blockIdx.x;       // (c,g) 0..511
    const int tid = threadIdx.x;
    const long R0 = (long)bid * 32;

    // load e tile [32,256]
#pragma unroll
    for (int i = 0; i < 32; i++) se[i][tid] = e[(R0 + i) * 256 + tid];
    __syncthreads();

    // S = e e^T / 16
    for (int p = tid; p < 1024; p += 256) {
        int n = p >> 5, m = p & 31;
        float s = 0.f;
#pragma unroll 8
        for (int o = 0; o < 256; o++) s += se[n][o] * se[m][o];
        satt[n][m] = s * (1.0f / 16.0f);
    }
    __syncthreads();

    // row softmax (32 rows)
    if (tid < 32) {
        int n = tid;
        float mx = -1e30f;
        for (int m = 0; m < 32; m++) mx = fmaxf(mx, satt[n][m]);
        float sum = 0.f;
        for (int m = 0; m < 32; m++) { float v = __expf(satt[n][m] - mx); satt[n][m] = v; sum += v; }
        float inv = 1.0f / sum;
        for (int m = 0; m < 32; m++) satt[n][m] *= inv;
    }
    __syncthreads();

    // ctx = att @ X  -> bf16
    for (int ch = 0; ch < 8; ch++) {
        int d = ch * 256 + tid;
        float acc[32];
#pragma unroll
        for (int n = 0; n < 32; n++) acc[n] = 0.f;
        for (int m = 0; m < 32; m++) {
            float x = X[(R0 + m) * C_D + d];
#pragma unroll
            for (int n = 0; n < 32; n++) acc[n] += satt[n][m] * x;
        }
#pragma unroll
        for (int n = 0; n < 32; n++) ctx[(R0 + n) * C_D + d] = (bf16)acc[n];
    }
}

// ---------------- p_e = P . W2^T (fp32, tiny) ----------------
__global__ __launch_bounds__(256) void pe_kernel(const float* __restrict__ P,
                                                 const float* __restrict__ W2,
                                                 float* __restrict__ p_e) {
    __shared__ float sp[C_D];
    const int row = blockIdx.x;   // c*5+p, 0..319
    const int tid = threadIdx.x;
    const float* pr = P + (long)row * C_D;
    for (int i = tid; i < C_D; i += 256) sp[i] = pr[i];
    __syncthreads();
    const float* w = W2 + (long)tid * C_D;
    float acc = 0.f;
    for (int k = 0; k < C_D; k += 4) {
        float4 wv = *(const float4*)&w[k];
        acc += sp[k] * wv.x + sp[k + 1] * wv.y + sp[k + 2] * wv.z + sp[k + 3] * wv.w;
    }
    p_e[(long)row * C_O + tid] = acc;
}

// ---------------- per-class inter attention + output (fp32) ----------------
__global__ __launch_bounds__(256) void inter_attn_kernel(const float* __restrict__ p_e,
                                                         const float* __restrict__ fa_e,
                                                         const bf16* __restrict__ Yb,
                                                         float* __restrict__ out) {
    __shared__ float spe[5][256];
    __shared__ float satt[5][256];
    __shared__ float red[256];
    const int c   = blockIdx.x;
    const int tid = threadIdx.x;

#pragma unroll
    for (int p = 0; p < 5; p++)
        spe[p][tid] = p_e[((long)c * 5 + p) * C_O + tid] * (1.0f / 16.0f);
    __syncthreads();

    // logits L[p][n], thread = n
    {
        const float* fa = fa_e + ((long)c * C_O + tid) * C_O;
        float acc[5] = {0.f, 0.f, 0.f, 0.f, 0.f};
        for (int o = 0; o < C_O; o++) {
            float f = fa[o];
#pragma unroll
            for (int p = 0; p < 5; p++) acc[p] += spe[p][o] * f;
        }
#pragma unroll
        for (int p = 0; p < 5; p++) satt[p][tid] = acc[p];
    }
    __syncthreads();

    // softmax over n (256) for each p
    for (int p = 0; p < 5; p++) {
        float v = satt[p][tid];
        red[tid] = v; __syncthreads();
        for (int s = 128; s > 0; s >>= 1) { if (tid < s) red[tid] = fmaxf(red[tid], red[tid + s]); __syncthreads(); }
        float mx = red[0]; __syncthreads();
        float ev = __expf(v - mx);
        red[tid] = ev; __syncthreads();
        for (int s = 128; s > 0; s >>= 1) { if (tid < s) red[tid] += red[tid + s]; __syncthreads(); }
        float sum = red[0]; __syncthreads();
        satt[p][tid] = ev / sum;
    }
    __syncthreads();

    // out[c,p,:] = att2 @ Y_c
    const bf16* Yc = Yb + (long)c * C_O * C_D;
    for (int ch = 0; ch < 8; ch++) {
        int d = ch * 256 + tid;
        float acc[5] = {0.f, 0.f, 0.f, 0.f, 0.f};
        for (int n = 0; n < C_O; n++) {
            float y = (float)Yc[(long)n * C_D + d];
#pragma unroll
            for (int p = 0; p < 5; p++) acc[p] += satt[p][n] * y;
        }
#pragma unroll
        for (int p = 0; p < 5; p++) out[((long)c * 5 + p) * C_D + d] = acc[p];
    }
}

extern "C" void kernel_launch(void* const* d_in, const int* in_sizes, int n_in,
                              void* d_out, int out_size, void* d_ws, size_t ws_size,
                              hipStream_t stream) {
    const float* X   = (const float*)d_in[0];  // [64,8,32,2048]
    const float* P   = (const float*)d_in[1];  // [64,5,2048]
    const float* W1  = (const float*)d_in[2];  // [256,2048] inner_w1
    const float* T   = (const float*)d_in[3];  // [2048,2048] inner_trans
    const float* Wi1 = (const float*)d_in[4];  // [256,2048] inter_w1
    const float* Wi2 = (const float*)d_in[5];  // [256,2048] inter_w2
    float* out = (float*)d_out;

    char* ws = (char*)d_ws;
    size_t off = 0;
    auto alloc = [&](size_t bytes) -> void* {
        void* p = ws + off;
        off += (bytes + 255) & ~(size_t)255;
        return p;
    };
    const size_t NX = (size_t)C_M * C_D;      // 33,554,432
    bf16*  Xb   = (bf16*)alloc(NX * 2);       // aliased: reused as ctx after K1
    bf16*  Tb   = (bf16*)alloc((size_t)C_D * C_D * 2);
    bf16*  W1b  = (bf16*)alloc((size_t)C_O * C_D * 2);
    bf16*  Wi1b = (bf16*)alloc((size_t)C_O * C_D * 2);
    bf16*  Yb   = (bf16*)alloc(NX * 2);
    float* eBuf = (float*)alloc((size_t)C_M * C_O * 4);   // aliased: reused as fa_e
    float* peBuf= (float*)alloc((size_t)C_CLASS * C_P * C_O * 4);
    bf16*  ctxb = Xb;     // Xb dead after K1
    float* faBuf= eBuf;   // e dead after K2

    // 1. convert inputs to bf16
    conv_kernel<<<(int)(NX / 1024), 256, 0, stream>>>(X, Xb, (int)(NX / 4));
    conv_kernel<<<C_D * C_D / 1024, 256, 0, stream>>>(T, Tb, C_D * C_D / 4);
    conv_kernel<<<C_O * C_D / 1024, 256, 0, stream>>>(W1, W1b, C_O * C_D / 4);
    conv_kernel<<<C_O * C_D / 1024, 256, 0, stream>>>(Wi1, Wi1b, C_O * C_D / 4);

    // 2. e = X . W1^T   [16384,256]
    gemm_nt<0><<<dim3(C_M / 128, C_O / 128), 256, 0, stream>>>(Xb, W1b, C_M, C_O, C_D, eBuf, nullptr, nullptr);

    // 3. inner attention -> ctx (bf16, overwrites Xb)
    inner_attn_kernel<<<C_CLASS * C_GROUPS, 256, 0, stream>>>(X, eBuf, ctxb);

    // 4. Y = bf16(X + relu(ctx . T^T))   [16384,2048]
    gemm_nt<1><<<dim3(C_M / 128, C_D / 128), 256, 0, stream>>>(ctxb, Tb, C_M, C_D, C_D, nullptr, Yb, X);

    // 5. fa_e = Y . Wi1^T   [16384,256] (overwrites eBuf)
    gemm_nt<0><<<dim3(C_M / 128, C_O / 128), 256, 0, stream>>>(Yb, Wi1b, C_M, C_O, C_D, faBuf, nullptr, nullptr);

    // 6. p_e = P . Wi2^T   [320,256]
    pe_kernel<<<C_CLASS * C_P, 256, 0, stream>>>(P, Wi2, peBuf);

    // 7. inter attention -> out [64,5,2048]
    inter_attn_kernel<<<C_CLASS, 256, 0, stream>>>(peBuf, faBuf, Yb, out);
}

// Round 2
// 839.141 us; speedup vs baseline: 1.2076x; 1.2076x over previous
//
#include <hip/hip_runtime.h>
#include <hip/hip_bf16.h>

// Problem constants
#define C_CLASS 64
#define C_GROUPS 8
#define C_GSIZE 32
#define C_D 2048      // IN_CH
#define C_O 256       // OUT_CH
#define C_P 5         // NUM_PROTO
#define C_M (C_CLASS*C_GROUPS*C_GSIZE)   // 16384 rows of feats

typedef __bf16 bf16;
typedef bf16 bf16x8 __attribute__((ext_vector_type(8)));
typedef bf16 bf16x4 __attribute__((ext_vector_type(4)));
typedef float floatx4 __attribute__((ext_vector_type(4)));

// async 16B global->LDS (m97 pattern: LDS dest must be uniform base + lane*16)
__device__ __forceinline__ void gl_lds16(const bf16* g, bf16* l) {
    __builtin_amdgcn_global_load_lds(
        (const __attribute__((address_space(1))) void*)g,
        (__attribute__((address_space(3))) void*)l, 16, 0, 0);
}

// ---------------- fp32 -> bf16 conversion (vectorized) ----------------
__global__ __launch_bounds__(256) void conv_kernel(const float* __restrict__ src,
                                                   bf16* __restrict__ dst, int n4) {
    int i = blockIdx.x * 256 + threadIdx.x;
    if (i < n4) {
        float4 v = ((const float4*)src)[i];
        bf16x4 b;
        b[0] = (bf16)v.x; b[1] = (bf16)v.y; b[2] = (bf16)v.z; b[3] = (bf16)v.w;
        ((bf16x4*)dst)[i] = b;
    }
}

// ---------------- 128x128 bf16 NT GEMM, global_load_lds staging ----------------
// EPI=0: Cf = acc (fp32). EPI=1: Cb = bf16(resid + relu(acc)).
template<int EPI>
__global__ __launch_bounds__(256) void gemm128(const bf16* __restrict__ A,
                                               const bf16* __restrict__ B,
                                               int M, int N, int K,
                                               float* __restrict__ Cf,
                                               bf16* __restrict__ Cb,
                                               const float* __restrict__ resid) {
    __shared__ bf16 sA[128 * 32];
    __shared__ bf16 sB[128 * 32];

    const int tid  = threadIdx.x;
    const int m0   = blockIdx.x * 128;
    const int n0   = blockIdx.y * 128;
    const int lane = tid & 63;
    const int wave = tid >> 6;
    const int wm   = (wave >> 1) * 64;
    const int wn   = (wave & 1) * 64;

    // staging map: thread tid -> LDS byte offset tid*16 (row tid>>2, col (tid&3)*8)
    const int sr = tid >> 2;
    const int sc = (tid & 3) * 8;
    const bf16* aP = A + (long)(m0 + sr) * K + sc;
    const bf16* bP = B + (long)(n0 + sr) * K + sc;
    bf16* sA0 = &sA[tid * 8];
    bf16* sA1 = &sA[2048 + tid * 8];
    bf16* sB0 = &sB[tid * 8];
    bf16* sB1 = &sB[2048 + tid * 8];

    floatx4 acc[4][4];
#pragma unroll
    for (int i = 0; i < 4; i++)
#pragma unroll
        for (int j = 0; j < 4; j++) acc[i][j] = (floatx4){0.f, 0.f, 0.f, 0.f};

    const int kk = (lane >> 4) * 8;
    const int rr = lane & 15;

    for (int k0 = 0; k0 < K; k0 += 32) {
        __syncthreads();
        gl_lds16(aP + k0, sA0);
        gl_lds16(aP + (long)64 * K + k0, sA1);
        gl_lds16(bP + k0, sB0);
        gl_lds16(bP + (long)64 * K + k0, sB1);
        __syncthreads();

        bf16x8 af[4], bff[4];
#pragma unroll
        for (int i = 0; i < 4; i++) {
            af[i]  = *(const bf16x8*)&sA[(wm + i * 16 + rr) * 32 + kk];
            bff[i] = *(const bf16x8*)&sB[(wn + i * 16 + rr) * 32 + kk];
        }
#pragma unroll
        for (int i = 0; i < 4; i++)
#pragma unroll
            for (int j = 0; j < 4; j++)
                acc[i][j] = __builtin_amdgcn_mfma_f32_16x16x32_bf16(af[i], bff[j], acc[i][j], 0, 0, 0);
    }

    const int cn    = lane & 15;
    const int rbase = (lane >> 4) * 4;
#pragma unroll
    for (int i = 0; i < 4; i++) {
#pragma unroll
        for (int j = 0; j < 4; j++) {
            int gn = n0 + wn + j * 16 + cn;
#pragma unroll
            for (int r = 0; r < 4; r++) {
                int gm = m0 + wm + i * 16 + rbase + r;
                long idx = (long)gm * N + gn;
                float v = acc[i][j][r];
                if (EPI == 0) Cf[idx] = v;
                else          Cb[idx] = (bf16)(resid[idx] + fmaxf(v, 0.f));
            }
        }
    }
}

// ---------------- 64x128 NT GEMM (for N=256 GEMMs), fp32 output ----------------
// AF32=1: A is fp32, converted to bf16 during staging (no separate conv pass).
template<int AF32>
__global__ __launch_bounds__(256) void gemm64(const void* __restrict__ Av,
                                              const bf16* __restrict__ B,
                                              int M, int N, int K,
                                              float* __restrict__ Cf) {
    __shared__ bf16 sA[64 * 32];
    __shared__ bf16 sB[128 * 32];

    const int tid  = threadIdx.x;
    const int m0   = blockIdx.x * 64;
    const int n0   = blockIdx.y * 128;
    const int lane = tid & 63;
    const int wave = tid >> 6;
    const int wm   = (wave >> 1) * 32;
    const int wn   = (wave & 1) * 64;

    const int sr = tid >> 2;          // 0..63
    const int sc = (tid & 3) * 8;
    const float* aPf = (const float*)Av + (long)(m0 + sr) * K + sc;
    const bf16*  aPb = (const bf16*)Av + (long)(m0 + sr) * K + sc;
    const bf16*  bP  = B + (long)(n0 + sr) * K + sc;
    bf16* sB0 = &sB[tid * 8];
    bf16* sB1 = &sB[2048 + tid * 8];

    floatx4 acc[2][4];
#pragma unroll
    for (int i = 0; i < 2; i++)
#pragma unroll
        for (int j = 0; j < 4; j++) acc[i][j] = (floatx4){0.f, 0.f, 0.f, 0.f};

    const int kk = (lane >> 4) * 8;
    const int rr = lane & 15;

    for (int k0 = 0; k0 < K; k0 += 32) {
        float4 xa0, xa1;
        if (AF32) {               // prefetch before barrier
            xa0 = *(const float4*)(aPf + k0);
            xa1 = *(const float4*)(aPf + k0 + 4);
        }
        __syncthreads();
        if (AF32) {
            bf16x8 v;
            v[0]=(bf16)xa0.x; v[1]=(bf16)xa0.y; v[2]=(bf16)xa0.z; v[3]=(bf16)xa0.w;
            v[4]=(bf16)xa1.x; v[5]=(bf16)xa1.y; v[6]=(bf16)xa1.z; v[7]=(bf16)xa1.w;
            *(bf16x8*)&sA[tid * 8] = v;
        } else {
            gl_lds16(aPb + k0, &sA[tid * 8]);
        }
        gl_lds16(bP + k0, sB0);
        gl_lds16(bP + (long)64 * K + k0, sB1);
        __syncthreads();

        bf16x8 af[2], bff[4];
#pragma unroll
        for (int i = 0; i < 2; i++)
            af[i] = *(const bf16x8*)&sA[(wm + i * 16 + rr) * 32 + kk];
#pragma unroll
        for (int j = 0; j < 4; j++)
            bff[j] = *(const bf16x8*)&sB[(wn + j * 16 + rr) * 32 + kk];
#pragma unroll
        for (int i = 0; i < 2; i++)
#pragma unroll
            for (int j = 0; j < 4; j++)
                acc[i][j] = __builtin_amdgcn_mfma_f32_16x16x32_bf16(af[i], bff[j], acc[i][j], 0, 0, 0);
    }

    const int cn    = lane & 15;
    const int rbase = (lane >> 4) * 4;
#pragma unroll
    for (int i = 0; i < 2; i++)
#pragma unroll
        for (int j = 0; j < 4; j++) {
            int gn = n0 + wn + j * 16 + cn;
#pragma unroll
            for (int r = 0; r < 4; r++) {
                int gm = m0 + wm + i * 16 + rbase + r;
                Cf[(long)gm * N + gn] = acc[i][j][r];
            }
        }
}

// ---------------- per-(c,g) inner attention (fp32), writes ctx as bf16 ----------------
__global__ __launch_bounds__(256) void inner_attn_kernel(const float* __restrict__ X,
                                                         const float* __restrict__ e,
                                                         bf16* __restrict__ ctx) {
    __shared__ float se[256][33];   // transposed: se[o][n]
    __shared__ float satt[32][33];
    const int bid = blockIdx.x;     // (c,g) 0..511
    const int tid = threadIdx.x;
    const long R0 = (long)bid * 32;

    // load e tile [32,256] transposed: se[tid][i] (bank (tid+i)%32 -> 2-way, free)
#pragma unroll
    for (int i = 0; i < 32; i++) se[tid][i] = e[(R0 + i) * 256 + tid];
    __syncthreads();

    // S[n][m] = <e_n, e_m>/16 : thread handles m=tid&31, n in {nb, nb+8, nb+16, nb+24}
    {
        const int m  = tid & 31;
        const int nb = tid >> 5;  // 0..7
        float s0 = 0.f, s1 = 0.f, s2 = 0.f, s3 = 0.f;
        for (int o = 0; o < 256; o++) {
            float em = se[o][m];                 // conflict-free (consecutive m)
            s0 += se[o][nb     ] * em;           // broadcast
            s1 += se[o][nb +  8] * em;
            s2 += se[o][nb + 16] * em;
            s3 += se[o][nb + 24] * em;
        }
        satt[nb     ][m] = s0 * (1.0f / 16.0f);
        satt[nb +  8][m] = s1 * (1.0f / 16.0f);
        satt[nb + 16][m] = s2 * (1.0f / 16.0f);
        satt[nb + 24][m] = s3 * (1.0f / 16.0f);
    }
    __syncthreads();

    // row softmax (32 rows)
    if (tid < 32) {
        int n = tid;
        float mx = -1e30f;
        for (int m = 0; m < 32; m++) mx = fmaxf(mx, satt[n][m]);
        float sum = 0.f;
        for (int m = 0; m < 32; m++) { float v = __expf(satt[n][m] - mx); satt[n][m] = v; sum += v; }
        float inv = 1.0f / sum;
        for (int m = 0; m < 32; m++) satt[n][m] *= inv;
    }
    __syncthreads();

    // ctx = att @ X  -> bf16
    for (int ch = 0; ch < 8; ch++) {
        int d = ch * 256 + tid;
        float acc[32];
#pragma unroll
        for (int n = 0; n < 32; n++) acc[n] = 0.f;
        for (int m = 0; m < 32; m++) {
            float x = X[(R0 + m) * C_D + d];
#pragma unroll
            for (int n = 0; n < 32; n++) acc[n] += satt[n][m] * x;
        }
#pragma unroll
        for (int n = 0; n < 32; n++) ctx[(R0 + n) * C_D + d] = (bf16)acc[n];
    }
}

// ---------------- p_e = P . W2^T (fp32, tiny) ----------------
__global__ __launch_bounds__(256) void pe_kernel(const float* __restrict__ P,
                                                 const float* __restrict__ W2,
                                                 float* __restrict__ p_e) {
    __shared__ float sp[C_D];
    const int row = blockIdx.x;   // c*5+p, 0..319
    const int tid = threadIdx.x;
    const float* pr = P + (long)row * C_D;
    for (int i = tid; i < C_D; i += 256) sp[i] = pr[i];
    __syncthreads();
    const float* w = W2 + (long)tid * C_D;
    float acc = 0.f;
    for (int k = 0; k < C_D; k += 4) {
        float4 wv = *(const float4*)&w[k];
        acc += sp[k] * wv.x + sp[k + 1] * wv.y + sp[k + 2] * wv.z + sp[k + 3] * wv.w;
    }
    p_e[(long)row * C_O + tid] = acc;
}

// ---------------- per-class inter attention + output (fp32) ----------------
// grid (64, 8): logits+softmax duplicated per d-chunk block (cheap), output split.
__global__ __launch_bounds__(256) void inter_attn_kernel(const float* __restrict__ p_e,
                                                         const float* __restrict__ fa_e,
                                                         const bf16* __restrict__ Yb,
                                                         float* __restrict__ out) {
    __shared__ float spe[5][256];
    __shared__ float satt[5][256];
    __shared__ float red[256];
    const int c   = blockIdx.x;
    const int ch  = blockIdx.y;
    const int tid = threadIdx.x;

#pragma unroll
    for (int p = 0; p < 5; p++)
        spe[p][tid] = p_e[((long)c * 5 + p) * C_O + tid] * (1.0f / 16.0f);
    __syncthreads();

    // logits L[p][n], thread = n
    {
        const float* fa = fa_e + ((long)c * C_O + tid) * C_O;
        float acc[5] = {0.f, 0.f, 0.f, 0.f, 0.f};
        for (int o = 0; o < C_O; o++) {
            float f = fa[o];
#pragma unroll
            for (int p = 0; p < 5; p++) acc[p] += spe[p][o] * f;
        }
#pragma unroll
        for (int p = 0; p < 5; p++) satt[p][tid] = acc[p];
    }
    __syncthreads();

    // softmax over n (256) for each p
    for (int p = 0; p < 5; p++) {
        float v = satt[p][tid];
        red[tid] = v; __syncthreads();
        for (int s = 128; s > 0; s >>= 1) { if (tid < s) red[tid] = fmaxf(red[tid], red[tid + s]); __syncthreads(); }
        float mx = red[0]; __syncthreads();
        float ev = __expf(v - mx);
        red[tid] = ev; __syncthreads();
        for (int s = 128; s > 0; s >>= 1) { if (tid < s) red[tid] += red[tid + s]; __syncthreads(); }
        float sum = red[0]; __syncthreads();
        satt[p][tid] = ev / sum;
    }
    __syncthreads();

    // out[c,p,d-chunk] = att2 @ Y_c
    const bf16* Yc = Yb + (long)c * C_O * C_D;
    const int d = ch * 256 + tid;
    float acc[5] = {0.f, 0.f, 0.f, 0.f, 0.f};
    for (int n = 0; n < C_O; n++) {
        float y = (float)Yc[(long)n * C_D + d];
#pragma unroll
        for (int p = 0; p < 5; p++) acc[p] += satt[p][n] * y;
    }
#pragma unroll
    for (int p = 0; p < 5; p++) out[((long)c * 5 + p) * C_D + d] = acc[p];
}

extern "C" void kernel_launch(void* const* d_in, const int* in_sizes, int n_in,
                              void* d_out, int out_size, void* d_ws, size_t ws_size,
                              hipStream_t stream) {
    const float* X   = (const float*)d_in[0];  // [64,8,32,2048]
    const float* P   = (const float*)d_in[1];  // [64,5,2048]
    const float* W1  = (const float*)d_in[2];  // [256,2048] inner_w1
    const float* T   = (const float*)d_in[3];  // [2048,2048] inner_trans
    const float* Wi1 = (const float*)d_in[4];  // [256,2048] inter_w1
    const float* Wi2 = (const float*)d_in[5];  // [256,2048] inter_w2
    float* out = (float*)d_out;

    char* ws = (char*)d_ws;
    size_t off = 0;
    auto alloc = [&](size_t bytes) -> void* {
        void* p = ws + off;
        off += (bytes + 255) & ~(size_t)255;
        return p;
    };
    const size_t NX = (size_t)C_M * C_D;
    bf16*  ctxb = (bf16*)alloc(NX * 2);
    bf16*  Tb   = (bf16*)alloc((size_t)C_D * C_D * 2);
    bf16*  W1b  = (bf16*)alloc((size_t)C_O * C_D * 2);
    bf16*  Wi1b = (bf16*)alloc((size_t)C_O * C_D * 2);
    bf16*  Yb   = (bf16*)alloc(NX * 2);
    float* eBuf = (float*)alloc((size_t)C_M * C_O * 4);   // aliased: reused as fa_e
    float* peBuf= (float*)alloc((size_t)C_CLASS * C_P * C_O * 4);
    float* faBuf= eBuf;   // e dead after inner_attn

    // 1. convert weights to bf16 (X converted in-kernel by gemm64<1>)
    conv_kernel<<<C_D * C_D / 1024, 256, 0, stream>>>(T, Tb, C_D * C_D / 4);
    conv_kernel<<<C_O * C_D / 1024, 256, 0, stream>>>(W1, W1b, C_O * C_D / 4);
    conv_kernel<<<C_O * C_D / 1024, 256, 0, stream>>>(Wi1, Wi1b, C_O * C_D / 4);

    // 2. e = X . W1^T   [16384,256]  (fp32 A staged+converted in-kernel)
    gemm64<1><<<dim3(C_M / 64, C_O / 128), 256, 0, stream>>>(X, W1b, C_M, C_O, C_D, eBuf);

    // 3. inner attention -> ctx (bf16)
    inner_attn_kernel<<<C_CLASS * C_GROUPS, 256, 0, stream>>>(X, eBuf, ctxb);

    // 4. Y = bf16(X + relu(ctx . T^T))   [16384,2048]
    gemm128<1><<<dim3(C_M / 128, C_D / 128), 256, 0, stream>>>(ctxb, Tb, C_M, C_D, C_D, nullptr, Yb, X);

    // 5. fa_e = Y . Wi1^T   [16384,256]
    gemm64<0><<<dim3(C_M / 64, C_O / 128), 256, 0, stream>>>(Yb, Wi1b, C_M, C_O, C_D, faBuf);

    // 6. p_e = P . Wi2^T   [320,256]
    pe_kernel<<<C_CLASS * C_P, 256, 0, stream>>>(P, Wi2, peBuf);

    // 7. inter attention -> out [64,5,2048]
    inter_attn_kernel<<<dim3(C_CLASS, 8), 256, 0, stream>>>(peBuf, faBuf, Yb, out);
}

// Round 4
// 737.535 us; speedup vs baseline: 1.3740x; 1.1378x over previous
//
#include <hip/hip_runtime.h>
#include <hip/hip_bf16.h>

// Problem constants
#define C_CLASS 64
#define C_GROUPS 8
#define C_GSIZE 32
#define C_D 2048      // IN_CH
#define C_O 256       // OUT_CH
#define C_P 5         // NUM_PROTO
#define C_M (C_CLASS*C_GROUPS*C_GSIZE)   // 16384 rows of feats

typedef __bf16 bf16;
typedef bf16 bf16x8 __attribute__((ext_vector_type(8)));
typedef bf16 bf16x4 __attribute__((ext_vector_type(4)));
typedef float floatx4 __attribute__((ext_vector_type(4)));

// async 16B global->LDS (LDS dest must be wave-uniform base + lane*16)
__device__ __forceinline__ void gl_lds16(const bf16* g, bf16* l) {
    __builtin_amdgcn_global_load_lds(
        (const __attribute__((address_space(1))) void*)g,
        (__attribute__((address_space(3))) void*)l, 16, 0, 0);
}

// ---------------- merged fp32 -> bf16 weight conversion ----------------
__global__ __launch_bounds__(256) void convw_kernel(const float* __restrict__ T,
                                                    const float* __restrict__ W1,
                                                    const float* __restrict__ Wi1,
                                                    bf16* __restrict__ Tb,
                                                    bf16* __restrict__ W1b,
                                                    bf16* __restrict__ Wi1b) {
    const int nT = C_D * C_D / 4;
    const int nW = C_O * C_D / 4;
    int i = blockIdx.x * 256 + threadIdx.x;
    const float* s; bf16* d; int j;
    if (i < nT)           { s = T;   d = Tb;   j = i; }
    else if (i < nT + nW) { s = W1;  d = W1b;  j = i - nT; }
    else                  { s = Wi1; d = Wi1b; j = i - nT - nW; }
    float4 v = ((const float4*)s)[j];
    bf16x4 b;
    b[0] = (bf16)v.x; b[1] = (bf16)v.y; b[2] = (bf16)v.z; b[3] = (bf16)v.w;
    ((bf16x4*)d)[j] = b;
}

// ---------------- 128x128 bf16 NT GEMM, BK=64, XOR-swizzled LDS ----------------
// LDS layout: chunk (row, c) of 8 bf16 holds global col-chunk c^(row&7).
// Staged via global_load_lds with permuted lane->global mapping (LDS side linear).
// EPI=0: Cf = acc (fp32). EPI=1: Cb = bf16(resid + relu(acc)).
template<int EPI>
__global__ __launch_bounds__(256) void gemm128(const bf16* __restrict__ A,
                                               const bf16* __restrict__ B,
                                               int M, int N, int K,
                                               float* __restrict__ Cf,
                                               bf16* __restrict__ Cb,
                                               const float* __restrict__ resid) {
    __shared__ bf16 sA[128 * 64];
    __shared__ bf16 sB[128 * 64];

    const int tid  = threadIdx.x;
    const int m0   = blockIdx.x * 128;
    const int n0   = blockIdx.y * 128;
    const int lane = tid & 63;
    const int wave = tid >> 6;
    const int wm   = (wave >> 1) * 64;
    const int wn   = (wave & 1) * 64;

    // staging: chunk u = tid + 256*s (s=0..3); row = u>>3 = (tid>>3)+32s,
    // global col-chunk cw = (tid&7) ^ (row&7)  [row&7 invariant in s]
    const int r0 = tid >> 3;
    const int cw = (tid & 7) ^ (r0 & 7);
    const bf16* aP = A + (long)(m0 + r0) * K + cw * 8;
    const bf16* bP = B + (long)(n0 + r0) * K + cw * 8;

    floatx4 acc[4][4];
#pragma unroll
    for (int i = 0; i < 4; i++)
#pragma unroll
        for (int j = 0; j < 4; j++) acc[i][j] = (floatx4){0.f, 0.f, 0.f, 0.f};

    const int rr  = lane & 15;
    const int q   = lane >> 4;
    const int swz = lane & 7;            // = (row m)&7 on the read side
    const int co0 = (q ^ swz) * 8;       // kh=0  (chunk q)
    const int co1 = ((q + 4) ^ swz) * 8; // kh=1  (chunk q+4)

    for (int k0 = 0; k0 < K; k0 += 64) {
        __syncthreads();
#pragma unroll
        for (int s = 0; s < 4; s++) {
            gl_lds16(aP + (long)(32 * s) * K + k0, &sA[(tid + 256 * s) * 8]);
            gl_lds16(bP + (long)(32 * s) * K + k0, &sB[(tid + 256 * s) * 8]);
        }
        __syncthreads();

#pragma unroll
        for (int kh = 0; kh < 2; kh++) {
            const int co = kh ? co1 : co0;
            bf16x8 af[4], bff[4];
#pragma unroll
            for (int i = 0; i < 4; i++) {
                af[i]  = *(const bf16x8*)&sA[(wm + i * 16 + rr) * 64 + co];
                bff[i] = *(const bf16x8*)&sB[(wn + i * 16 + rr) * 64 + co];
            }
#pragma unroll
            for (int i = 0; i < 4; i++)
#pragma unroll
                for (int j = 0; j < 4; j++)
                    acc[i][j] = __builtin_amdgcn_mfma_f32_16x16x32_bf16(af[i], bff[j], acc[i][j], 0, 0, 0);
        }
    }

    // epilogue: C/D layout col=lane&15, row=(lane>>4)*4+reg
    const int cn    = lane & 15;
    const int rbase = (lane >> 4) * 4;
#pragma unroll
    for (int i = 0; i < 4; i++) {
#pragma unroll
        for (int j = 0; j < 4; j++) {
            int gn = n0 + wn + j * 16 + cn;
#pragma unroll
            for (int r = 0; r < 4; r++) {
                int gm = m0 + wm + i * 16 + rbase + r;
                long idx = (long)gm * N + gn;
                float v = acc[i][j][r];
                if (EPI == 0) Cf[idx] = v;
                else          Cb[idx] = (bf16)(resid[idx] + fmaxf(v, 0.f));
            }
        }
    }
}

// ---------------- 64x128 NT GEMM (N=256 GEMMs), BK=64, swizzled; fp32 out ----------------
// AF32=1: A is fp32, converted to bf16 during staging (ds_write side, same swizzle).
template<int AF32>
__global__ __launch_bounds__(256) void gemm64(const void* __restrict__ Av,
                                              const bf16* __restrict__ B,
                                              int M, int N, int K,
                                              float* __restrict__ Cf) {
    __shared__ bf16 sA[64 * 64];    // 8 KB
    __shared__ bf16 sB[128 * 64];   // 16 KB

    const int tid  = threadIdx.x;
    const int m0   = blockIdx.x * 64;
    const int n0   = blockIdx.y * 128;
    const int lane = tid & 63;
    const int wave = tid >> 6;
    const int wm   = (wave >> 1) * 32;
    const int wn   = (wave & 1) * 64;

    const int r0 = tid >> 3;
    const int cw = (tid & 7) ^ (r0 & 7);
    const float* aPf = (const float*)Av + (long)(m0 + r0) * K + cw * 8;
    const bf16*  aPb = (const bf16*)Av + (long)(m0 + r0) * K + cw * 8;
    const bf16*  bP  = B + (long)(n0 + r0) * K + cw * 8;

    floatx4 acc[2][4];
#pragma unroll
    for (int i = 0; i < 2; i++)
#pragma unroll
        for (int j = 0; j < 4; j++) acc[i][j] = (floatx4){0.f, 0.f, 0.f, 0.f};

    const int rr  = lane & 15;
    const int q   = lane >> 4;
    const int swz = lane & 7;
    const int co0 = (q ^ swz) * 8;
    const int co1 = ((q + 4) ^ swz) * 8;

    for (int k0 = 0; k0 < K; k0 += 64) {
        float4 xa[2][2];
        if (AF32) {
#pragma unroll
            for (int s = 0; s < 2; s++) {
                xa[s][0] = *(const float4*)(aPf + (long)(32 * s) * K + k0);
                xa[s][1] = *(const float4*)(aPf + (long)(32 * s) * K + k0 + 4);
            }
        }
        __syncthreads();
        if (AF32) {
#pragma unroll
            for (int s = 0; s < 2; s++) {
                bf16x8 v;
                v[0]=(bf16)xa[s][0].x; v[1]=(bf16)xa[s][0].y; v[2]=(bf16)xa[s][0].z; v[3]=(bf16)xa[s][0].w;
                v[4]=(bf16)xa[s][1].x; v[5]=(bf16)xa[s][1].y; v[6]=(bf16)xa[s][1].z; v[7]=(bf16)xa[s][1].w;
                *(bf16x8*)&sA[(tid + 256 * s) * 8] = v;
            }
        } else {
#pragma unroll
            for (int s = 0; s < 2; s++)
                gl_lds16(aPb + (long)(32 * s) * K + k0, &sA[(tid + 256 * s) * 8]);
        }
#pragma unroll
        for (int s = 0; s < 4; s++)
            gl_lds16(bP + (long)(32 * s) * K + k0, &sB[(tid + 256 * s) * 8]);
        __syncthreads();

#pragma unroll
        for (int kh = 0; kh < 2; kh++) {
            const int co = kh ? co1 : co0;
            bf16x8 af[2], bff[4];
#pragma unroll
            for (int i = 0; i < 2; i++)
                af[i] = *(const bf16x8*)&sA[(wm + i * 16 + rr) * 64 + co];
#pragma unroll
            for (int j = 0; j < 4; j++)
                bff[j] = *(const bf16x8*)&sB[(wn + j * 16 + rr) * 64 + co];
#pragma unroll
            for (int i = 0; i < 2; i++)
#pragma unroll
                for (int j = 0; j < 4; j++)
                    acc[i][j] = __builtin_amdgcn_mfma_f32_16x16x32_bf16(af[i], bff[j], acc[i][j], 0, 0, 0);
        }
    }

    const int cn    = lane & 15;
    const int rbase = (lane >> 4) * 4;
#pragma unroll
    for (int i = 0; i < 2; i++)
#pragma unroll
        for (int j = 0; j < 4; j++) {
            int gn = n0 + wn + j * 16 + cn;
#pragma unroll
            for (int r = 0; r < 4; r++) {
                int gm = m0 + wm + i * 16 + rbase + r;
                Cf[(long)gm * N + gn] = acc[i][j][r];
            }
        }
}

// ---------------- per-(c,g) inner attention (fp32), writes ctx as bf16 ----------------
__global__ __launch_bounds__(256) void inner_attn_kernel(const float* __restrict__ X,
                                                         const float* __restrict__ e,
                                                         bf16* __restrict__ ctx) {
    __shared__ float se[256][33];   // transposed: se[o][n]
    __shared__ float satt[32][33];
    const int bid = blockIdx.x;     // (c,g) 0..511
    const int tid = threadIdx.x;
    const long R0 = (long)bid * 32;

#pragma unroll
    for (int i = 0; i < 32; i++) se[tid][i] = e[(R0 + i) * 256 + tid];
    __syncthreads();

    {
        const int m  = tid & 31;
        const int nb = tid >> 5;
        float s0 = 0.f, s1 = 0.f, s2 = 0.f, s3 = 0.f;
        for (int o = 0; o < 256; o++) {
            float em = se[o][m];
            s0 += se[o][nb     ] * em;
            s1 += se[o][nb +  8] * em;
            s2 += se[o][nb + 16] * em;
            s3 += se[o][nb + 24] * em;
        }
        satt[nb     ][m] = s0 * (1.0f / 16.0f);
        satt[nb +  8][m] = s1 * (1.0f / 16.0f);
        satt[nb + 16][m] = s2 * (1.0f / 16.0f);
        satt[nb + 24][m] = s3 * (1.0f / 16.0f);
    }
    __syncthreads();

    if (tid < 32) {
        int n = tid;
        float mx = -1e30f;
        for (int m = 0; m < 32; m++) mx = fmaxf(mx, satt[n][m]);
        float sum = 0.f;
        for (int m = 0; m < 32; m++) { float v = __expf(satt[n][m] - mx); satt[n][m] = v; sum += v; }
        float inv = 1.0f / sum;
        for (int m = 0; m < 32; m++) satt[n][m] *= inv;
    }
    __syncthreads();

    for (int ch = 0; ch < 8; ch++) {
        int d = ch * 256 + tid;
        float acc[32];
#pragma unroll
        for (int n = 0; n < 32; n++) acc[n] = 0.f;
        for (int m = 0; m < 32; m++) {
            float x = X[(R0 + m) * C_D + d];
#pragma unroll
            for (int n = 0; n < 32; n++) acc[n] += satt[n][m] * x;
        }
#pragma unroll
        for (int n = 0; n < 32; n++) ctx[(R0 + n) * C_D + d] = (bf16)acc[n];
    }
}

// ---------------- p_e = P . W2^T, one block per class ----------------
__global__ __launch_bounds__(256) void pe_kernel(const float* __restrict__ P,
                                                 const float* __restrict__ W2,
                                                 float* __restrict__ p_e) {
    __shared__ float sp[5][C_D];    // 40 KB
    const int c   = blockIdx.x;
    const int tid = threadIdx.x;
    for (int t = tid; t < 5 * C_D; t += 256)
        sp[t >> 11][t & (C_D - 1)] = P[(long)c * 5 * C_D + t];
    __syncthreads();
    const float* w = W2 + (long)tid * C_D;
    float acc[5] = {0.f, 0.f, 0.f, 0.f, 0.f};
    for (int k = 0; k < C_D; k += 4) {
        float4 wv = *(const float4*)&w[k];
#pragma unroll
        for (int p = 0; p < 5; p++)
            acc[p] += sp[p][k] * wv.x + sp[p][k+1] * wv.y + sp[p][k+2] * wv.z + sp[p][k+3] * wv.w;
    }
#pragma unroll
    for (int p = 0; p < 5; p++)
        p_e[((long)c * 5 + p) * C_O + tid] = acc[p];
}

// ---------------- per-class inter attention + output, grid 64 x 1024 thr ----------------
__global__ __launch_bounds__(1024) void inter_attn_kernel(const float* __restrict__ p_e,
                                                          const float* __restrict__ fa_e,
                                                          const bf16* __restrict__ Yb,
                                                          float* __restrict__ out) {
    __shared__ float spe[5][256];
    __shared__ float part[4][5][256];
    __shared__ float att[5][256];
    __shared__ float red[256];
    const int c   = blockIdx.x;
    const int tid = threadIdx.x;

    // FIX (R3 bug): 1280 elements, 1024 threads -> strided loop, not a guard.
    for (int t = tid; t < 5 * 256; t += 1024)
        spe[t >> 8][t & 255] = p_e[(long)c * 5 * 256 + t] * (1.0f / 16.0f);
    __syncthreads();

    // logits: thread (n = tid&255, quarter qq = tid>>8) does 64 o's
    {
        const int n  = tid & 255;
        const int qq = tid >> 8;
        const float* fa = fa_e + ((long)c * 256 + n) * 256;
        float acc[5] = {0.f, 0.f, 0.f, 0.f, 0.f};
        for (int o = qq * 64; o < qq * 64 + 64; o++) {
            float f = fa[o];
#pragma unroll
            for (int p = 0; p < 5; p++) acc[p] += spe[p][o] * f;
        }
#pragma unroll
        for (int p = 0; p < 5; p++) part[qq][p][n] = acc[p];
    }
    __syncthreads();
    if (tid < 256) {
#pragma unroll
        for (int p = 0; p < 5; p++)
            att[p][tid] = part[0][p][tid] + part[1][p][tid] + part[2][p][tid] + part[3][p][tid];
    }
    __syncthreads();

    // softmax over n=256 per p (all 1024 threads hit every barrier)
    for (int p = 0; p < 5; p++) {
        float v = (tid < 256) ? att[p][tid] : -1e30f;
        if (tid < 256) red[tid] = v;
        __syncthreads();
        for (int s = 128; s > 0; s >>= 1) {
            if (tid < s) red[tid] = fmaxf(red[tid], red[tid + s]);
            __syncthreads();
        }
        float mx = red[0]; __syncthreads();
        float ev = __expf(v - mx);
        if (tid < 256) red[tid] = ev;
        __syncthreads();
        for (int s = 128; s > 0; s >>= 1) {
            if (tid < s) red[tid] += red[tid + s];
            __syncthreads();
        }
        float sum = red[0]; __syncthreads();
        if (tid < 256) att[p][tid] = ev / sum;
    }
    __syncthreads();

    // out[c,p,:] = att2 @ Y_c   (1024 threads cover d in 2 passes)
    const bf16* Yc = Yb + (long)c * C_O * C_D;
#pragma unroll
    for (int dp = 0; dp < 2; dp++) {
        int d = dp * 1024 + tid;
        float acc[5] = {0.f, 0.f, 0.f, 0.f, 0.f};
        for (int n = 0; n < C_O; n++) {
            float y = (float)Yc[(long)n * C_D + d];
#pragma unroll
            for (int p = 0; p < 5; p++) acc[p] += att[p][n] * y;
        }
#pragma unroll
        for (int p = 0; p < 5; p++) out[((long)c * 5 + p) * C_D + d] = acc[p];
    }
}

extern "C" void kernel_launch(void* const* d_in, const int* in_sizes, int n_in,
                              void* d_out, int out_size, void* d_ws, size_t ws_size,
                              hipStream_t stream) {
    const float* X   = (const float*)d_in[0];
    const float* P   = (const float*)d_in[1];
    const float* W1  = (const float*)d_in[2];
    const float* T   = (const float*)d_in[3];
    const float* Wi1 = (const float*)d_in[4];
    const float* Wi2 = (const float*)d_in[5];
    float* out = (float*)d_out;

    char* ws = (char*)d_ws;
    size_t off = 0;
    auto alloc = [&](size_t bytes) -> void* {
        void* p = ws + off;
        off += (bytes + 255) & ~(size_t)255;
        return p;
    };
    const size_t NX = (size_t)C_M * C_D;
    bf16*  ctxb = (bf16*)alloc(NX * 2);
    bf16*  Tb   = (bf16*)alloc((size_t)C_D * C_D * 2);
    bf16*  W1b  = (bf16*)alloc((size_t)C_O * C_D * 2);
    bf16*  Wi1b = (bf16*)alloc((size_t)C_O * C_D * 2);
    bf16*  Yb   = (bf16*)alloc(NX * 2);
    float* eBuf = (float*)alloc((size_t)C_M * C_O * 4);
    float* peBuf= (float*)alloc((size_t)C_CLASS * C_P * C_O * 4);
    float* faBuf= eBuf;   // e dead after inner_attn

    // 1. weights -> bf16 (single merged launch)
    const int nConv4 = (C_D * C_D + 2 * C_O * C_D) / 4;
    convw_kernel<<<nConv4 / 256, 256, 0, stream>>>(T, W1, Wi1, Tb, W1b, Wi1b);

    // 2. e = X . W1^T   [16384,256]  (fp32 A staged+converted in-kernel)
    gemm64<1><<<dim3(C_M / 64, C_O / 128), 256, 0, stream>>>(X, W1b, C_M, C_O, C_D, eBuf);

    // 3. inner attention -> ctx (bf16)
    inner_attn_kernel<<<C_CLASS * C_GROUPS, 256, 0, stream>>>(X, eBuf, ctxb);

    // 4. Y = bf16(X + relu(ctx . T^T))   [16384,2048]
    gemm128<1><<<dim3(C_M / 128, C_D / 128), 256, 0, stream>>>(ctxb, Tb, C_M, C_D, C_D, nullptr, Yb, X);

    // 5. fa_e = Y . Wi1^T   [16384,256]
    gemm64<0><<<dim3(C_M / 64, C_O / 128), 256, 0, stream>>>(Yb, Wi1b, C_M, C_O, C_D, faBuf);

    // 6. p_e = P . Wi2^T   [320,256]  (one block per class)
    pe_kernel<<<C_CLASS, 256, 0, stream>>>(P, Wi2, peBuf);

    // 7. inter attention -> out [64,5,2048]
    inter_attn_kernel<<<C_CLASS, 1024, 0, stream>>>(peBuf, faBuf, Yb, out);
}

// Round 5
// 712.965 us; speedup vs baseline: 1.4213x; 1.0345x over previous
//
#include <hip/hip_runtime.h>
#include <hip/hip_bf16.h>

// Problem constants
#define C_CLASS 64
#define C_GROUPS 8
#define C_GSIZE 32
#define C_D 2048      // IN_CH
#define C_O 256       // OUT_CH
#define C_P 5         // NUM_PROTO
#define C_M (C_CLASS*C_GROUPS*C_GSIZE)   // 16384 rows of feats

typedef __bf16 bf16;
typedef bf16 bf16x8 __attribute__((ext_vector_type(8)));
typedef bf16 bf16x4 __attribute__((ext_vector_type(4)));
typedef float floatx4 __attribute__((ext_vector_type(4)));

// async 16B global->LDS (LDS dest must be wave-uniform base + lane*16)
__device__ __forceinline__ void gl_lds16(const bf16* g, bf16* l) {
    __builtin_amdgcn_global_load_lds(
        (const __attribute__((address_space(1))) void*)g,
        (__attribute__((address_space(3))) void*)l, 16, 0, 0);
}

// ---------------- merged fp32 -> bf16 weight conversion ----------------
__global__ __launch_bounds__(256) void convw_kernel(const float* __restrict__ T,
                                                    const float* __restrict__ W1,
                                                    const float* __restrict__ Wi1,
                                                    bf16* __restrict__ Tb,
                                                    bf16* __restrict__ W1b,
                                                    bf16* __restrict__ Wi1b) {
    const int nT = C_D * C_D / 4;
    const int nW = C_O * C_D / 4;
    int i = blockIdx.x * 256 + threadIdx.x;
    const float* s; bf16* d; int j;
    if (i < nT)           { s = T;   d = Tb;   j = i; }
    else if (i < nT + nW) { s = W1;  d = W1b;  j = i - nT; }
    else                  { s = Wi1; d = Wi1b; j = i - nT - nW; }
    float4 v = ((const float4*)s)[j];
    bf16x4 b;
    b[0] = (bf16)v.x; b[1] = (bf16)v.y; b[2] = (bf16)v.z; b[3] = (bf16)v.w;
    ((bf16x4*)d)[j] = b;
}

// ---------------- big GEMM: Yb = bf16(residb + relu(ctx . T^T)) ----------------
// M=16384, N=2048, K=2048. 128x128 tile, BK=64, XOR-swizzled LDS (R4-verified).
// 1-D grid (2048) with GROUP_M=8 rasterization: co-XCD blocks (id mod 8) share
// the same A-tile -> A fetched ~once per XCD L2 instead of 16x.
__global__ __launch_bounds__(256) void gemm_relu(const bf16* __restrict__ A,
                                                 const bf16* __restrict__ B,
                                                 const bf16* __restrict__ residb,
                                                 bf16* __restrict__ Cb) {
    __shared__ bf16 sA[128 * 64];
    __shared__ bf16 sB[128 * 64];

    const int tid = threadIdx.x;
    // decode: window = 128 blocks (8 m-rows x 16 n-cols)
    const int id  = blockIdx.x;
    const int grp = id >> 7;
    const int rem = id & 127;
    const int m0  = ((grp << 3) + (rem & 7)) << 7;   // 0..127 * 128
    const int n0  = (rem >> 3) << 7;                 // 0..15  * 128

    const int lane = tid & 63;
    const int wave = tid >> 6;
    const int wm   = (wave >> 1) * 64;
    const int wn   = (wave & 1) * 64;

    // staging: chunk u = tid + 256*s; row = (tid>>3)+32s, col-chunk cw = (tid&7)^(row&7)
    const int r0 = tid >> 3;
    const int cw = (tid & 7) ^ (r0 & 7);
    const bf16* aP = A + (long)(m0 + r0) * C_D + cw * 8;
    const bf16* bP = B + (long)(n0 + r0) * C_D + cw * 8;

    floatx4 acc[4][4];
#pragma unroll
    for (int i = 0; i < 4; i++)
#pragma unroll
        for (int j = 0; j < 4; j++) acc[i][j] = (floatx4){0.f, 0.f, 0.f, 0.f};

    const int rr  = lane & 15;
    const int q   = lane >> 4;
    const int swz = lane & 7;
    const int co0 = (q ^ swz) * 8;
    const int co1 = ((q + 4) ^ swz) * 8;

    for (int k0 = 0; k0 < C_D; k0 += 64) {
        __syncthreads();
#pragma unroll
        for (int s = 0; s < 4; s++) {
            gl_lds16(aP + (long)(32 * s) * C_D + k0, &sA[(tid + 256 * s) * 8]);
            gl_lds16(bP + (long)(32 * s) * C_D + k0, &sB[(tid + 256 * s) * 8]);
        }
        __syncthreads();

#pragma unroll
        for (int kh = 0; kh < 2; kh++) {
            const int co = kh ? co1 : co0;
            bf16x8 af[4], bff[4];
#pragma unroll
            for (int i = 0; i < 4; i++) {
                af[i]  = *(const bf16x8*)&sA[(wm + i * 16 + rr) * 64 + co];
                bff[i] = *(const bf16x8*)&sB[(wn + i * 16 + rr) * 64 + co];
            }
#pragma unroll
            for (int i = 0; i < 4; i++)
#pragma unroll
                for (int j = 0; j < 4; j++)
                    acc[i][j] = __builtin_amdgcn_mfma_f32_16x16x32_bf16(af[i], bff[j], acc[i][j], 0, 0, 0);
        }
    }

    // epilogue: C/D layout col=lane&15, row=(lane>>4)*4+reg; resid is bf16 now
    const int cn    = lane & 15;
    const int rbase = (lane >> 4) * 4;
#pragma unroll
    for (int i = 0; i < 4; i++) {
#pragma unroll
        for (int j = 0; j < 4; j++) {
            int gn = n0 + wn + j * 16 + cn;
#pragma unroll
            for (int r = 0; r < 4; r++) {
                int gm = m0 + wm + i * 16 + rbase + r;
                long idx = (long)gm * C_D + gn;
                Cb[idx] = (bf16)((float)residb[idx] + fmaxf(acc[i][j][r], 0.f));
            }
        }
    }
}

// ---------------- 64x128 NT GEMM (M=16384, N=256, K=2048), fp32 out ----------------
// AF32=1: A is fp32, converted to bf16 during staging; blocks with n0==0 also
// emit the converted A as Xout (bf16) for downstream consumers.
template<int AF32>
__global__ __launch_bounds__(256) void gemm64(const void* __restrict__ Av,
                                              const bf16* __restrict__ B,
                                              float* __restrict__ Cf,
                                              bf16* __restrict__ Xout) {
    __shared__ bf16 sA[64 * 64];    // 8 KB
    __shared__ bf16 sB[128 * 64];   // 16 KB

    const int tid  = threadIdx.x;
    const int m0   = blockIdx.x * 64;
    const int n0   = blockIdx.y * 128;
    const int lane = tid & 63;
    const int wave = tid >> 6;
    const int wm   = (wave >> 1) * 32;
    const int wn   = (wave & 1) * 64;

    const int r0 = tid >> 3;
    const int cw = (tid & 7) ^ (r0 & 7);
    const float* aPf = (const float*)Av + (long)(m0 + r0) * C_D + cw * 8;
    const bf16*  aPb = (const bf16*)Av + (long)(m0 + r0) * C_D + cw * 8;
    const bf16*  bP  = B + (long)(n0 + r0) * C_D + cw * 8;
    const bool   wrX = AF32 && (n0 == 0) && (Xout != nullptr);

    floatx4 acc[2][4];
#pragma unroll
    for (int i = 0; i < 2; i++)
#pragma unroll
        for (int j = 0; j < 4; j++) acc[i][j] = (floatx4){0.f, 0.f, 0.f, 0.f};

    const int rr  = lane & 15;
    const int q   = lane >> 4;
    const int swz = lane & 7;
    const int co0 = (q ^ swz) * 8;
    const int co1 = ((q + 4) ^ swz) * 8;

    for (int k0 = 0; k0 < C_D; k0 += 64) {
        float4 xa[2][2];
        if (AF32) {
#pragma unroll
            for (int s = 0; s < 2; s++) {
                xa[s][0] = *(const float4*)(aPf + (long)(32 * s) * C_D + k0);
                xa[s][1] = *(const float4*)(aPf + (long)(32 * s) * C_D + k0 + 4);
            }
        }
        __syncthreads();
        if (AF32) {
#pragma unroll
            for (int s = 0; s < 2; s++) {
                bf16x8 v;
                v[0]=(bf16)xa[s][0].x; v[1]=(bf16)xa[s][0].y; v[2]=(bf16)xa[s][0].z; v[3]=(bf16)xa[s][0].w;
                v[4]=(bf16)xa[s][1].x; v[5]=(bf16)xa[s][1].y; v[6]=(bf16)xa[s][1].z; v[7]=(bf16)xa[s][1].w;
                *(bf16x8*)&sA[(tid + 256 * s) * 8] = v;
                if (wrX)
                    *(bf16x8*)&Xout[(long)(m0 + r0 + 32 * s) * C_D + k0 + cw * 8] = v;
            }
        } else {
#pragma unroll
            for (int s = 0; s < 2; s++)
                gl_lds16(aPb + (long)(32 * s) * C_D + k0, &sA[(tid + 256 * s) * 8]);
        }
#pragma unroll
        for (int s = 0; s < 4; s++)
            gl_lds16(bP + (long)(32 * s) * C_D + k0, &sB[(tid + 256 * s) * 8]);
        __syncthreads();

#pragma unroll
        for (int kh = 0; kh < 2; kh++) {
            const int co = kh ? co1 : co0;
            bf16x8 af[2], bff[4];
#pragma unroll
            for (int i = 0; i < 2; i++)
                af[i] = *(const bf16x8*)&sA[(wm + i * 16 + rr) * 64 + co];
#pragma unroll
            for (int j = 0; j < 4; j++)
                bff[j] = *(const bf16x8*)&sB[(wn + j * 16 + rr) * 64 + co];
#pragma unroll
            for (int i = 0; i < 2; i++)
#pragma unroll
                for (int j = 0; j < 4; j++)
                    acc[i][j] = __builtin_amdgcn_mfma_f32_16x16x32_bf16(af[i], bff[j], acc[i][j], 0, 0, 0);
        }
    }

    const int cn    = lane & 15;
    const int rbase = (lane >> 4) * 4;
#pragma unroll
    for (int i = 0; i < 2; i++)
#pragma unroll
        for (int j = 0; j < 4; j++) {
            int gn = n0 + wn + j * 16 + cn;
#pragma unroll
            for (int r = 0; r < 4; r++) {
                int gm = m0 + wm + i * 16 + rbase + r;
                Cf[(long)gm * C_O + gn] = acc[i][j][r];
            }
        }
}

// ---------------- per-(c,g) inner attention; X read as bf16 ----------------
__global__ __launch_bounds__(256) void inner_attn_kernel(const bf16* __restrict__ Xb,
                                                         const float* __restrict__ e,
                                                         bf16* __restrict__ ctx) {
    __shared__ float se[256][33];   // transposed: se[o][n]
    __shared__ float satt[32][33];
    const int bid = blockIdx.x;     // (c,g) 0..511
    const int tid = threadIdx.x;
    const long R0 = (long)bid * 32;

#pragma unroll
    for (int i = 0; i < 32; i++) se[tid][i] = e[(R0 + i) * 256 + tid];
    __syncthreads();

    {
        const int m  = tid & 31;
        const int nb = tid >> 5;
        float s0 = 0.f, s1 = 0.f, s2 = 0.f, s3 = 0.f;
        for (int o = 0; o < 256; o++) {
            float em = se[o][m];
            s0 += se[o][nb     ] * em;
            s1 += se[o][nb +  8] * em;
            s2 += se[o][nb + 16] * em;
            s3 += se[o][nb + 24] * em;
        }
        satt[nb     ][m] = s0 * (1.0f / 16.0f);
        satt[nb +  8][m] = s1 * (1.0f / 16.0f);
        satt[nb + 16][m] = s2 * (1.0f / 16.0f);
        satt[nb + 24][m] = s3 * (1.0f / 16.0f);
    }
    __syncthreads();

    if (tid < 32) {
        int n = tid;
        float mx = -1e30f;
        for (int m = 0; m < 32; m++) mx = fmaxf(mx, satt[n][m]);
        float sum = 0.f;
        for (int m = 0; m < 32; m++) { float v = __expf(satt[n][m] - mx); satt[n][m] = v; sum += v; }
        float inv = 1.0f / sum;
        for (int m = 0; m < 32; m++) satt[n][m] *= inv;
    }
    __syncthreads();

    for (int ch = 0; ch < 8; ch++) {
        int d = ch * 256 + tid;
        float acc[32];
#pragma unroll
        for (int n = 0; n < 32; n++) acc[n] = 0.f;
        for (int m = 0; m < 32; m++) {
            float x = (float)Xb[(R0 + m) * C_D + d];
#pragma unroll
            for (int n = 0; n < 32; n++) acc[n] += satt[n][m] * x;
        }
#pragma unroll
        for (int n = 0; n < 32; n++) ctx[(R0 + n) * C_D + d] = (bf16)acc[n];
    }
}

// ---------------- per-class: p_e + inter attention + output (fused) ----------------
__global__ __launch_bounds__(1024) void inter_attn_kernel(const float* __restrict__ P,
                                                          const float* __restrict__ W2,
                                                          const float* __restrict__ fa_e,
                                                          const bf16* __restrict__ Yb,
                                                          float* __restrict__ out) {
    __shared__ float sp[5][C_D];       // 40 KB prototypes (fp32)
    __shared__ float spe[5][256];
    __shared__ float part[4][5][256];
    __shared__ float att[5][256];
    __shared__ float red[256];
    const int c   = blockIdx.x;
    const int tid = threadIdx.x;

    for (int t = tid; t < 5 * C_D; t += 1024)
        sp[t >> 11][t & (C_D - 1)] = P[(long)c * 5 * C_D + t];
    __syncthreads();

    // p_e[p][o] = <P[c,p,:], W2[o,:]> : thread (o = tid&255, qq = tid>>8) does 512 k's
    {
        const int o  = tid & 255;
        const int qq = tid >> 8;
        const float* w = W2 + (long)o * C_D + qq * 512;
        float acc[5] = {0.f, 0.f, 0.f, 0.f, 0.f};
        for (int k = 0; k < 512; k += 4) {
            float4 wv = *(const float4*)&w[k];
            int kk = qq * 512 + k;
#pragma unroll
            for (int p = 0; p < 5; p++)
                acc[p] += sp[p][kk] * wv.x + sp[p][kk+1] * wv.y + sp[p][kk+2] * wv.z + sp[p][kk+3] * wv.w;
        }
#pragma unroll
        for (int p = 0; p < 5; p++) part[qq][p][o] = acc[p];
    }
    __syncthreads();
    if (tid < 256) {
#pragma unroll
        for (int p = 0; p < 5; p++)
            spe[p][tid] = (part[0][p][tid] + part[1][p][tid] + part[2][p][tid] + part[3][p][tid])
                          * (1.0f / 16.0f);
    }
    __syncthreads();

    // logits: thread (n = tid&255, quarter qq) does 64 o's
    {
        const int n  = tid & 255;
        const int qq = tid >> 8;
        const float* fa = fa_e + ((long)c * 256 + n) * 256;
        float acc[5] = {0.f, 0.f, 0.f, 0.f, 0.f};
        for (int o = qq * 64; o < qq * 64 + 64; o++) {
            float f = fa[o];
#pragma unroll
            for (int p = 0; p < 5; p++) acc[p] += spe[p][o] * f;
        }
#pragma unroll
        for (int p = 0; p < 5; p++) part[qq][p][n] = acc[p];
    }
    __syncthreads();
    if (tid < 256) {
#pragma unroll
        for (int p = 0; p < 5; p++)
            att[p][tid] = part[0][p][tid] + part[1][p][tid] + part[2][p][tid] + part[3][p][tid];
    }
    __syncthreads();

    // softmax over n=256 per p
    for (int p = 0; p < 5; p++) {
        float v = (tid < 256) ? att[p][tid] : -1e30f;
        if (tid < 256) red[tid] = v;
        __syncthreads();
        for (int s = 128; s > 0; s >>= 1) {
            if (tid < s) red[tid] = fmaxf(red[tid], red[tid + s]);
            __syncthreads();
        }
        float mx = red[0]; __syncthreads();
        float ev = __expf(v - mx);
        if (tid < 256) red[tid] = ev;
        __syncthreads();
        for (int s = 128; s > 0; s >>= 1) {
            if (tid < s) red[tid] += red[tid + s];
            __syncthreads();
        }
        float sum = red[0]; __syncthreads();
        if (tid < 256) att[p][tid] = ev / sum;
    }
    __syncthreads();

    // out[c,p,:] = att2 @ Y_c
    const bf16* Yc = Yb + (long)c * C_O * C_D;
#pragma unroll
    for (int dp = 0; dp < 2; dp++) {
        int d = dp * 1024 + tid;
        float acc[5] = {0.f, 0.f, 0.f, 0.f, 0.f};
        for (int n = 0; n < C_O; n++) {
            float y = (float)Yc[(long)n * C_D + d];
#pragma unroll
            for (int p = 0; p < 5; p++) acc[p] += att[p][n] * y;
        }
#pragma unroll
        for (int p = 0; p < 5; p++) out[((long)c * 5 + p) * C_D + d] = acc[p];
    }
}

extern "C" void kernel_launch(void* const* d_in, const int* in_sizes, int n_in,
                              void* d_out, int out_size, void* d_ws, size_t ws_size,
                              hipStream_t stream) {
    const float* X   = (const float*)d_in[0];
    const float* P   = (const float*)d_in[1];
    const float* W1  = (const float*)d_in[2];
    const float* T   = (const float*)d_in[3];
    const float* Wi1 = (const float*)d_in[4];
    const float* Wi2 = (const float*)d_in[5];
    float* out = (float*)d_out;

    char* ws = (char*)d_ws;
    size_t off = 0;
    auto alloc = [&](size_t bytes) -> void* {
        void* p = ws + off;
        off += (bytes + 255) & ~(size_t)255;
        return p;
    };
    const size_t NX = (size_t)C_M * C_D;
    bf16*  Xb   = (bf16*)alloc(NX * 2);       // bf16 copy of X (emitted by e-GEMM)
    bf16*  ctxb = (bf16*)alloc(NX * 2);
    bf16*  Tb   = (bf16*)alloc((size_t)C_D * C_D * 2);
    bf16*  W1b  = (bf16*)alloc((size_t)C_O * C_D * 2);
    bf16*  Wi1b = (bf16*)alloc((size_t)C_O * C_D * 2);
    bf16*  Yb   = (bf16*)alloc(NX * 2);
    float* eBuf = (float*)alloc((size_t)C_M * C_O * 4);
    float* faBuf= eBuf;   // e dead after inner_attn

    // 1. weights -> bf16 (single merged launch)
    const int nConv4 = (C_D * C_D + 2 * C_O * C_D) / 4;
    convw_kernel<<<nConv4 / 256, 256, 0, stream>>>(T, W1, Wi1, Tb, W1b, Wi1b);

    // 2. e = X . W1^T  [16384,256]; also emits Xb (bf16) from the n0==0 blocks
    gemm64<1><<<dim3(C_M / 64, C_O / 128), 256, 0, stream>>>(X, W1b, eBuf, Xb);

    // 3. inner attention -> ctx (bf16), X read as bf16
    inner_attn_kernel<<<C_CLASS * C_GROUPS, 256, 0, stream>>>(Xb, eBuf, ctxb);

    // 4. Y = bf16(Xb + relu(ctx . T^T))  [16384,2048], swizzled 1-D grid
    gemm_relu<<<(C_M / 128) * (C_D / 128), 256, 0, stream>>>(ctxb, Tb, Xb, Yb);

    // 5. fa_e = Y . Wi1^T  [16384,256]
    gemm64<0><<<dim3(C_M / 64, C_O / 128), 256, 0, stream>>>(Yb, Wi1b, faBuf, nullptr);

    // 6. fused p_e + inter attention -> out [64,5,2048]
    inter_attn_kernel<<<C_CLASS, 1024, 0, stream>>>(P, Wi2, faBuf, Yb, out);
}

// Round 6
// 564.676 us; speedup vs baseline: 1.7946x; 1.2626x over previous
//
#include <hip/hip_runtime.h>
#include <hip/hip_bf16.h>

// Problem constants
#define C_CLASS 64
#define C_GROUPS 8
#define C_GSIZE 32
#define C_D 2048      // IN_CH
#define C_O 256       // OUT_CH
#define C_P 5         // NUM_PROTO
#define C_M (C_CLASS*C_GROUPS*C_GSIZE)   // 16384 rows of feats

typedef __bf16 bf16;
typedef bf16 bf16x8 __attribute__((ext_vector_type(8)));
typedef bf16 bf16x4 __attribute__((ext_vector_type(4)));
typedef float floatx4 __attribute__((ext_vector_type(4)));

// async 16B global->LDS (LDS dest must be wave-uniform base + lane*16)
__device__ __forceinline__ void gl_lds16(const bf16* g, bf16* l) {
    __builtin_amdgcn_global_load_lds(
        (const __attribute__((address_space(1))) void*)g,
        (__attribute__((address_space(3))) void*)l, 16, 0, 0);
}

// ---------------- merged fp32 -> bf16 weight conversion (T, W1, Wi1, W2) ----------------
__global__ __launch_bounds__(256) void convw_kernel(const float* __restrict__ T,
                                                    const float* __restrict__ W1,
                                                    const float* __restrict__ Wi1,
                                                    const float* __restrict__ W2,
                                                    bf16* __restrict__ Tb,
                                                    bf16* __restrict__ W1b,
                                                    bf16* __restrict__ Wi1b,
                                                    bf16* __restrict__ W2b) {
    const int nT = C_D * C_D / 4;
    const int nW = C_O * C_D / 4;
    int i = blockIdx.x * 256 + threadIdx.x;
    const float* s; bf16* d; int j;
    if (i < nT)               { s = T;   d = Tb;   j = i; }
    else if (i < nT + nW)     { s = W1;  d = W1b;  j = i - nT; }
    else if (i < nT + 2 * nW) { s = Wi1; d = Wi1b; j = i - nT - nW; }
    else                      { s = W2;  d = W2b;  j = i - nT - 2 * nW; }
    float4 v = ((const float4*)s)[j];
    bf16x4 b;
    b[0] = (bf16)v.x; b[1] = (bf16)v.y; b[2] = (bf16)v.z; b[3] = (bf16)v.w;
    ((bf16x4*)d)[j] = b;
}

// ---------------- big GEMM: Yb = bf16(residb + relu(ctx . T^T)) ----------------
// (R5-verified: BK=64 XOR-swizzle, GROUP_M=8 raster, 808 TF)
__global__ __launch_bounds__(256) void gemm_relu(const bf16* __restrict__ A,
                                                 const bf16* __restrict__ B,
                                                 const bf16* __restrict__ residb,
                                                 bf16* __restrict__ Cb) {
    __shared__ bf16 sA[128 * 64];
    __shared__ bf16 sB[128 * 64];

    const int tid = threadIdx.x;
    const int id  = blockIdx.x;
    const int grp = id >> 7;
    const int rem = id & 127;
    const int m0  = ((grp << 3) + (rem & 7)) << 7;
    const int n0  = (rem >> 3) << 7;

    const int lane = tid & 63;
    const int wave = tid >> 6;
    const int wm   = (wave >> 1) * 64;
    const int wn   = (wave & 1) * 64;

    const int r0 = tid >> 3;
    const int cw = (tid & 7) ^ (r0 & 7);
    const bf16* aP = A + (long)(m0 + r0) * C_D + cw * 8;
    const bf16* bP = B + (long)(n0 + r0) * C_D + cw * 8;

    floatx4 acc[4][4];
#pragma unroll
    for (int i = 0; i < 4; i++)
#pragma unroll
        for (int j = 0; j < 4; j++) acc[i][j] = (floatx4){0.f, 0.f, 0.f, 0.f};

    const int rr  = lane & 15;
    const int q   = lane >> 4;
    const int swz = lane & 7;
    const int co0 = (q ^ swz) * 8;
    const int co1 = ((q + 4) ^ swz) * 8;

    for (int k0 = 0; k0 < C_D; k0 += 64) {
        __syncthreads();
#pragma unroll
        for (int s = 0; s < 4; s++) {
            gl_lds16(aP + (long)(32 * s) * C_D + k0, &sA[(tid + 256 * s) * 8]);
            gl_lds16(bP + (long)(32 * s) * C_D + k0, &sB[(tid + 256 * s) * 8]);
        }
        __syncthreads();

#pragma unroll
        for (int kh = 0; kh < 2; kh++) {
            const int co = kh ? co1 : co0;
            bf16x8 af[4], bff[4];
#pragma unroll
            for (int i = 0; i < 4; i++) {
                af[i]  = *(const bf16x8*)&sA[(wm + i * 16 + rr) * 64 + co];
                bff[i] = *(const bf16x8*)&sB[(wn + i * 16 + rr) * 64 + co];
            }
#pragma unroll
            for (int i = 0; i < 4; i++)
#pragma unroll
                for (int j = 0; j < 4; j++)
                    acc[i][j] = __builtin_amdgcn_mfma_f32_16x16x32_bf16(af[i], bff[j], acc[i][j], 0, 0, 0);
        }
    }

    const int cn    = lane & 15;
    const int rbase = (lane >> 4) * 4;
#pragma unroll
    for (int i = 0; i < 4; i++) {
#pragma unroll
        for (int j = 0; j < 4; j++) {
            int gn = n0 + wn + j * 16 + cn;
#pragma unroll
            for (int r = 0; r < 4; r++) {
                int gm = m0 + wm + i * 16 + rbase + r;
                long idx = (long)gm * C_D + gn;
                Cb[idx] = (bf16)((float)residb[idx] + fmaxf(acc[i][j][r], 0.f));
            }
        }
    }
}

// ---------------- 64x128 NT GEMM (N=256, K=2048), fp32 out ----------------
// AF32=1: A fp32, converted during staging; n0==0 blocks optionally emit Xout (bf16).
template<int AF32>
__global__ __launch_bounds__(256) void gemm64(const void* __restrict__ Av,
                                              const bf16* __restrict__ B,
                                              float* __restrict__ Cf,
                                              bf16* __restrict__ Xout) {
    __shared__ bf16 sA[64 * 64];
    __shared__ bf16 sB[128 * 64];

    const int tid  = threadIdx.x;
    const int m0   = blockIdx.x * 64;
    const int n0   = blockIdx.y * 128;
    const int lane = tid & 63;
    const int wave = tid >> 6;
    const int wm   = (wave >> 1) * 32;
    const int wn   = (wave & 1) * 64;

    const int r0 = tid >> 3;
    const int cw = (tid & 7) ^ (r0 & 7);
    const float* aPf = (const float*)Av + (long)(m0 + r0) * C_D + cw * 8;
    const bf16*  aPb = (const bf16*)Av + (long)(m0 + r0) * C_D + cw * 8;
    const bf16*  bP  = B + (long)(n0 + r0) * C_D + cw * 8;
    const bool   wrX = AF32 && (n0 == 0) && (Xout != nullptr);

    floatx4 acc[2][4];
#pragma unroll
    for (int i = 0; i < 2; i++)
#pragma unroll
        for (int j = 0; j < 4; j++) acc[i][j] = (floatx4){0.f, 0.f, 0.f, 0.f};

    const int rr  = lane & 15;
    const int q   = lane >> 4;
    const int swz = lane & 7;
    const int co0 = (q ^ swz) * 8;
    const int co1 = ((q + 4) ^ swz) * 8;

    for (int k0 = 0; k0 < C_D; k0 += 64) {
        float4 xa[2][2];
        if (AF32) {
#pragma unroll
            for (int s = 0; s < 2; s++) {
                xa[s][0] = *(const float4*)(aPf + (long)(32 * s) * C_D + k0);
                xa[s][1] = *(const float4*)(aPf + (long)(32 * s) * C_D + k0 + 4);
            }
        }
        __syncthreads();
        if (AF32) {
#pragma unroll
            for (int s = 0; s < 2; s++) {
                bf16x8 v;
                v[0]=(bf16)xa[s][0].x; v[1]=(bf16)xa[s][0].y; v[2]=(bf16)xa[s][0].z; v[3]=(bf16)xa[s][0].w;
                v[4]=(bf16)xa[s][1].x; v[5]=(bf16)xa[s][1].y; v[6]=(bf16)xa[s][1].z; v[7]=(bf16)xa[s][1].w;
                *(bf16x8*)&sA[(tid + 256 * s) * 8] = v;
                if (wrX)
                    *(bf16x8*)&Xout[(long)(m0 + r0 + 32 * s) * C_D + k0 + cw * 8] = v;
            }
        } else {
#pragma unroll
            for (int s = 0; s < 2; s++)
                gl_lds16(aPb + (long)(32 * s) * C_D + k0, &sA[(tid + 256 * s) * 8]);
        }
#pragma unroll
        for (int s = 0; s < 4; s++)
            gl_lds16(bP + (long)(32 * s) * C_D + k0, &sB[(tid + 256 * s) * 8]);
        __syncthreads();

#pragma unroll
        for (int kh = 0; kh < 2; kh++) {
            const int co = kh ? co1 : co0;
            bf16x8 af[2], bff[4];
#pragma unroll
            for (int i = 0; i < 2; i++)
                af[i] = *(const bf16x8*)&sA[(wm + i * 16 + rr) * 64 + co];
#pragma unroll
            for (int j = 0; j < 4; j++)
                bff[j] = *(const bf16x8*)&sB[(wn + j * 16 + rr) * 64 + co];
#pragma unroll
            for (int i = 0; i < 2; i++)
#pragma unroll
                for (int j = 0; j < 4; j++)
                    acc[i][j] = __builtin_amdgcn_mfma_f32_16x16x32_bf16(af[i], bff[j], acc[i][j], 0, 0, 0);
        }
    }

    const int cn    = lane & 15;
    const int rbase = (lane >> 4) * 4;
#pragma unroll
    for (int i = 0; i < 2; i++)
#pragma unroll
        for (int j = 0; j < 4; j++) {
            int gn = n0 + wn + j * 16 + cn;
#pragma unroll
            for (int r = 0; r < 4; r++) {
                int gm = m0 + wm + i * 16 + rbase + r;
                Cf[(long)gm * C_O + gn] = acc[i][j][r];
            }
        }
}

// ---------------- per-(c,g) S + softmax -> att (bf16) ----------------
__global__ __launch_bounds__(256) void att_kernel(const float* __restrict__ e,
                                                  bf16* __restrict__ attb) {
    __shared__ float se[256][33];   // transposed: se[o][n]
    __shared__ float satt[32][33];
    const int g   = blockIdx.x;     // 0..511
    const int tid = threadIdx.x;
    const long R0 = (long)g * 32;

#pragma unroll
    for (int i = 0; i < 32; i++) se[tid][i] = e[(R0 + i) * 256 + tid];
    __syncthreads();

    {
        const int m  = tid & 31;
        const int nb = tid >> 5;
        float s0 = 0.f, s1 = 0.f, s2 = 0.f, s3 = 0.f;
        for (int o = 0; o < 256; o++) {
            float em = se[o][m];
            s0 += se[o][nb     ] * em;
            s1 += se[o][nb +  8] * em;
            s2 += se[o][nb + 16] * em;
            s3 += se[o][nb + 24] * em;
        }
        satt[nb     ][m] = s0 * (1.0f / 16.0f);
        satt[nb +  8][m] = s1 * (1.0f / 16.0f);
        satt[nb + 16][m] = s2 * (1.0f / 16.0f);
        satt[nb + 24][m] = s3 * (1.0f / 16.0f);
    }
    __syncthreads();

    if (tid < 32) {
        int n = tid;
        float mx = -1e30f;
        for (int m = 0; m < 32; m++) mx = fmaxf(mx, satt[n][m]);
        float sum = 0.f;
        for (int m = 0; m < 32; m++) { float v = __expf(satt[n][m] - mx); satt[n][m] = v; sum += v; }
        float inv = 1.0f / sum;
        for (int m = 0; m < 32; m++) satt[n][m] *= inv;
    }
    __syncthreads();

    // write att row-major [n][m] as bf16 (4 elems/thread, no row crossing: 4|32)
    {
        const int base = tid * 4;
        const int n = base >> 5, m = base & 31;
        bf16x4 v;
        v[0] = (bf16)satt[n][m];     v[1] = (bf16)satt[n][m + 1];
        v[2] = (bf16)satt[n][m + 2]; v[3] = (bf16)satt[n][m + 3];
        *(bf16x4*)&attb[(long)g * 1024 + base] = v;
    }
}

// ---------------- ctx = att @ X via MFMA, grid (512 groups, 8 d-chunks) ----------------
// Per block: [32x32]bf16 @ [32x256]bf16 -> ctx[32x256]. X tile staged in LDS with
// stride 258 (transposed B-frag reads conflict-free: quads offset 8 banks).
__global__ __launch_bounds__(256) void ctx_kernel(const bf16* __restrict__ attb,
                                                  const bf16* __restrict__ Xb,
                                                  bf16* __restrict__ ctx) {
    __shared__ bf16 sX[32 * 258];
    const int g   = blockIdx.x;
    const int dch = blockIdx.y;
    const int tid = threadIdx.x;
    const long R0 = (long)g * 32;
    const int d0  = dch * 256;

    // stage X tile [32 rows x 256 cols]
    {
        const int r  = tid >> 3;
        const int c0 = (tid & 7) * 32;
        const bf16* src = Xb + (R0 + r) * C_D + d0 + c0;
#pragma unroll
        for (int i = 0; i < 4; i++) {
            bf16x8 v = *(const bf16x8*)(src + i * 8);
            *(bf16x8*)&sX[r * 258 + c0 + i * 8] = v;
        }
    }
    __syncthreads();

    const int lane = tid & 63;
    const int wave = tid >> 6;
    const int rr   = lane & 15;
    const int q    = lane >> 4;

    // A-frags straight from global (att is L2-hot, 16B/lane)
    bf16x8 af[2];
#pragma unroll
    for (int i = 0; i < 2; i++)
        af[i] = *(const bf16x8*)&attb[(long)g * 1024 + (i * 16 + rr) * 32 + q * 8];

    floatx4 acc[2][4];
#pragma unroll
    for (int i = 0; i < 2; i++)
#pragma unroll
        for (int j = 0; j < 4; j++) acc[i][j] = (floatx4){0.f, 0.f, 0.f, 0.f};

#pragma unroll
    for (int j = 0; j < 4; j++) {
        const int dl = wave * 64 + j * 16 + rr;
        bf16x8 bf_;
#pragma unroll
        for (int jj = 0; jj < 8; jj++)
            bf_[jj] = sX[(q * 8 + jj) * 258 + dl];
#pragma unroll
        for (int i = 0; i < 2; i++)
            acc[i][j] = __builtin_amdgcn_mfma_f32_16x16x32_bf16(af[i], bf_, acc[i][j], 0, 0, 0);
    }

    const int rbase = q * 4;
#pragma unroll
    for (int i = 0; i < 2; i++)
#pragma unroll
        for (int j = 0; j < 4; j++)
#pragma unroll
            for (int r = 0; r < 4; r++)
                ctx[(R0 + i * 16 + rbase + r) * C_D + d0 + wave * 64 + j * 16 + rr]
                    = (bf16)acc[i][j][r];
}

// ---------------- att2: logits + softmax per class (64 blocks x 256) ----------------
__global__ __launch_bounds__(256) void att2_kernel(const float* __restrict__ p_e,
                                                   const float* __restrict__ fa_e,
                                                   float* __restrict__ att2f) {
    __shared__ float spe[5][256];
    __shared__ float red[256];
    __shared__ float att[5][256];
    const int c   = blockIdx.x;
    const int tid = threadIdx.x;

    for (int t = tid; t < 5 * 256; t += 256)
        spe[t >> 8][t & 255] = p_e[(long)c * 5 * 256 + t] * (1.0f / 16.0f);
    __syncthreads();

    // logits: thread = n, float4 over o
    {
        const float4* fa = (const float4*)(fa_e + ((long)c * 256 + tid) * 256);
        float acc[5] = {0.f, 0.f, 0.f, 0.f, 0.f};
        for (int o4 = 0; o4 < 64; o4++) {
            float4 f = fa[o4];
#pragma unroll
            for (int p = 0; p < 5; p++) {
                float4 s = *(const float4*)&spe[p][o4 * 4];
                acc[p] += s.x * f.x + s.y * f.y + s.z * f.z + s.w * f.w;
            }
        }
#pragma unroll
        for (int p = 0; p < 5; p++) att[p][tid] = acc[p];
    }
    __syncthreads();

    for (int p = 0; p < 5; p++) {
        float v = att[p][tid];
        red[tid] = v; __syncthreads();
        for (int s = 128; s > 0; s >>= 1) { if (tid < s) red[tid] = fmaxf(red[tid], red[tid + s]); __syncthreads(); }
        float mx = red[0]; __syncthreads();
        float ev = __expf(v - mx);
        red[tid] = ev; __syncthreads();
        for (int s = 128; s > 0; s >>= 1) { if (tid < s) red[tid] += red[tid + s]; __syncthreads(); }
        float sum = red[0]; __syncthreads();
        att2f[((long)c * 5 + p) * 256 + tid] = ev / sum;
    }
}

// ---------------- out = att2 @ Y, grid (64 classes, 8 d-chunks) x 256 ----------------
__global__ __launch_bounds__(256) void out_kernel(const float* __restrict__ att2f,
                                                  const bf16* __restrict__ Yb,
                                                  float* __restrict__ out) {
    __shared__ float s2[5][256];
    const int c   = blockIdx.x;
    const int ch  = blockIdx.y;
    const int tid = threadIdx.x;

    for (int t = tid; t < 5 * 256; t += 256)
        s2[t >> 8][t & 255] = att2f[(long)c * 5 * 256 + t];
    __syncthreads();

    const int d = ch * 256 + tid;
    const bf16* Yc = Yb + (long)c * C_O * C_D + d;
    float acc[5] = {0.f, 0.f, 0.f, 0.f, 0.f};
    for (int n4 = 0; n4 < 64; n4++) {
        float y0 = (float)Yc[(long)(n4 * 4 + 0) * C_D];
        float y1 = (float)Yc[(long)(n4 * 4 + 1) * C_D];
        float y2 = (float)Yc[(long)(n4 * 4 + 2) * C_D];
        float y3 = (float)Yc[(long)(n4 * 4 + 3) * C_D];
#pragma unroll
        for (int p = 0; p < 5; p++) {
            float4 a = *(const float4*)&s2[p][n4 * 4];
            acc[p] += a.x * y0 + a.y * y1 + a.z * y2 + a.w * y3;
        }
    }
#pragma unroll
    for (int p = 0; p < 5; p++)
        out[((long)c * 5 + p) * C_D + d] = acc[p];
}

extern "C" void kernel_launch(void* const* d_in, const int* in_sizes, int n_in,
                              void* d_out, int out_size, void* d_ws, size_t ws_size,
                              hipStream_t stream) {
    const float* X   = (const float*)d_in[0];
    const float* P   = (const float*)d_in[1];
    const float* W1  = (const float*)d_in[2];
    const float* T   = (const float*)d_in[3];
    const float* Wi1 = (const float*)d_in[4];
    const float* Wi2 = (const float*)d_in[5];
    float* out = (float*)d_out;

    char* ws = (char*)d_ws;
    size_t off = 0;
    auto alloc = [&](size_t bytes) -> void* {
        void* p = ws + off;
        off += (bytes + 255) & ~(size_t)255;
        return p;
    };
    const size_t NX = (size_t)C_M * C_D;
    bf16*  Xb   = (bf16*)alloc(NX * 2);
    bf16*  ctxb = (bf16*)alloc(NX * 2);
    bf16*  Tb   = (bf16*)alloc((size_t)C_D * C_D * 2);
    bf16*  W1b  = (bf16*)alloc((size_t)C_O * C_D * 2);
    bf16*  Wi1b = (bf16*)alloc((size_t)C_O * C_D * 2);
    bf16*  W2b  = (bf16*)alloc((size_t)C_O * C_D * 2);
    bf16*  Yb   = (bf16*)alloc(NX * 2);
    float* eBuf = (float*)alloc((size_t)C_M * C_O * 4);
    bf16*  attb = (bf16*)alloc((size_t)512 * 1024 * 2);   // aliased: att2f after ctx
    float* peBuf= (float*)alloc((size_t)C_CLASS * C_P * C_O * 4);
    float* faBuf = eBuf;            // e dead after att_kernel
    float* att2f = (float*)attb;    // attb dead after ctx_kernel (0.33MB < 1MB)

    // 1. weights -> bf16
    const int nConv4 = (C_D * C_D + 3 * C_O * C_D) / 4;
    convw_kernel<<<nConv4 / 256, 256, 0, stream>>>(T, W1, Wi1, Wi2, Tb, W1b, Wi1b, W2b);

    // 2. e = X . W1^T [16384,256]; n0==0 blocks emit Xb
    gemm64<1><<<dim3(C_M / 64, 2), 256, 0, stream>>>(X, W1b, eBuf, Xb);

    // 3. S + softmax -> att (bf16)
    att_kernel<<<C_CLASS * C_GROUPS, 256, 0, stream>>>(eBuf, attb);

    // 4. ctx = att @ X (batched MFMA)
    ctx_kernel<<<dim3(C_CLASS * C_GROUPS, 8), 256, 0, stream>>>(attb, Xb, ctxb);

    // 5. Y = bf16(Xb + relu(ctx . T^T))
    gemm_relu<<<(C_M / 128) * (C_D / 128), 256, 0, stream>>>(ctxb, Tb, Xb, Yb);

    // 6. fa_e = Y . Wi1^T [16384,256]
    gemm64<0><<<dim3(C_M / 64, 2), 256, 0, stream>>>(Yb, Wi1b, faBuf, nullptr);

    // 7. p_e = P . W2^T [320,256] (M=320 = 5 blocks)
    gemm64<1><<<dim3(C_CLASS * C_P / 64, 2), 256, 0, stream>>>(P, W2b, peBuf, nullptr);

    // 8. att2 = softmax(p_e . fa_e^T / 16)
    att2_kernel<<<C_CLASS, 256, 0, stream>>>(peBuf, faBuf, att2f);

    // 9. out = att2 @ Y
    out_kernel<<<dim3(C_CLASS, 8), 256, 0, stream>>>(att2f, Yb, out);
}